// Round 13
// baseline (348.103 us; speedup 1.0000x reference)
//
#include <hip/hip_runtime.h>
#include <hip/hip_bf16.h>

// DataEncoder: normalize(log CPM) -> GCN(BN,LeakyReLU) x2 -> loc/std heads

typedef float f32x4 __attribute__((ext_vector_type(4)));
typedef __bf16 bf16x8 __attribute__((ext_vector_type(8)));

#define AS1 __attribute__((address_space(1)))
#define AS3 __attribute__((address_space(3)))

__device__ __forceinline__ void gload_lds16(const void* g, void* l) {
  __builtin_amdgcn_global_load_lds((AS1 void*)(g), (AS3 void*)(l), 16, 0, 0);
}

__device__ __forceinline__ unsigned short f2bu(float f) {
  return __builtin_bit_cast(unsigned short, __float2bfloat16(f));
}
__device__ __forceinline__ float b2f(unsigned short u) {
  return __uint_as_float(((unsigned)u) << 16);
}

__device__ __forceinline__ void unpack8(uint4 v, float* f) {
  f[0] = __uint_as_float(v.x << 16);
  f[1] = __uint_as_float(v.x & 0xffff0000u);
  f[2] = __uint_as_float(v.y << 16);
  f[3] = __uint_as_float(v.y & 0xffff0000u);
  f[4] = __uint_as_float(v.z << 16);
  f[5] = __uint_as_float(v.z & 0xffff0000u);
  f[6] = __uint_as_float(v.w << 16);
  f[7] = __uint_as_float(v.w & 0xffff0000u);
}

// ---- fused: weight prep (transpose+bf16) + zero(deg) --------------------
__global__ void prep_zero_k(const float* __restrict__ W1, const float* __restrict__ W2,
                            const float* __restrict__ Wloc, const float* __restrict__ Wstd,
                            unsigned short* __restrict__ W1T, unsigned short* __restrict__ W2T,
                            unsigned short* __restrict__ WcT, int* __restrict__ deg, int n) {
  int id = blockIdx.x * 256 + threadIdx.x;
  if (id < 262144) {                       // W1T [256][1024] (K padded 1000->1024)
    int nn = id >> 10, k = id & 1023;
    W1T[nn * 1024 + k] = (k < 1000) ? f2bu(W1[k * 256 + nn]) : (unsigned short)0;
  } else if (id < 262144 + 65536) {        // W2T [256][256]
    int id2 = id - 262144;
    int nn = id2 >> 8, k = id2 & 255;
    W2T[nn * 256 + k] = f2bu(W2[k * 256 + nn]);
  } else if (id < 262144 + 65536 + 16384) {// WcatT [64][256]: cols 0-31 loc, 32-63 std
    int id3 = id - 262144 - 65536;
    int j = id3 >> 8, k = id3 & 255;
    float v = (j < 32) ? Wloc[k * 32 + j] : Wstd[k * 32 + (j - 32)];
    WcT[j * 256 + k] = f2bu(v);
  } else {                                 // zero deg
    int id4 = id - 344064;
    if (id4 < n) deg[id4] = 0;
  }
}

// ---- fused: row sums+normalize (blocks < RB) || deg atomics (blocks >= RB) ----
__global__ __launch_bounds__(256) void rowsum_deg_k(const float* __restrict__ X,
                                                    float* __restrict__ out_l,
                                                    unsigned short* __restrict__ xb, int n,
                                                    const int* __restrict__ ei, int E,
                                                    int* __restrict__ deg, int RB) {
  if (blockIdx.x >= RB) {  // deg histogram part
    int e = (blockIdx.x - RB) * 256 + threadIdx.x;
    int stride = (gridDim.x - RB) * 256;
    for (; e < E; e += stride) atomicAdd(&deg[ei[E + e]], 1);
    return;
  }
  int gtid = blockIdx.x * 256 + threadIdx.x;
  int wave = gtid >> 6, lane = gtid & 63;
  int nw = (RB * 256) >> 6;
  for (int r = wave; r < n; r += nw) {
    const float4* xr = (const float4*)(X + (size_t)r * 1000);
    float4 v0 = xr[lane];
    float4 v1 = xr[lane + 64];
    float4 v2 = xr[lane + 128];
    float4 v3 = (lane < 58) ? xr[lane + 192] : make_float4(0.f, 0.f, 0.f, 0.f);
    float s = ((v0.x + v0.y) + (v0.z + v0.w)) + ((v1.x + v1.y) + (v1.z + v1.w)) +
              ((v2.x + v2.y) + (v2.z + v2.w)) + ((v3.x + v3.y) + (v3.z + v3.w));
#pragma unroll
    for (int o2 = 32; o2 > 0; o2 >>= 1) s += __shfl_xor(s, o2, 64);
    if (lane == 0) out_l[r] = s;
    float sc = 10000.f / s;
    unsigned short* xrow = xb + (size_t)r * 1024;
    ushort4 b;
    b.x = f2bu(__logf(fmaf(v0.x, sc, 1.f)));
    b.y = f2bu(__logf(fmaf(v0.y, sc, 1.f)));
    b.z = f2bu(__logf(fmaf(v0.z, sc, 1.f)));
    b.w = f2bu(__logf(fmaf(v0.w, sc, 1.f)));
    *(ushort4*)(xrow + lane * 4) = b;
    b.x = f2bu(__logf(fmaf(v1.x, sc, 1.f)));
    b.y = f2bu(__logf(fmaf(v1.y, sc, 1.f)));
    b.z = f2bu(__logf(fmaf(v1.z, sc, 1.f)));
    b.w = f2bu(__logf(fmaf(v1.w, sc, 1.f)));
    *(ushort4*)(xrow + (lane + 64) * 4) = b;
    b.x = f2bu(__logf(fmaf(v2.x, sc, 1.f)));
    b.y = f2bu(__logf(fmaf(v2.y, sc, 1.f)));
    b.z = f2bu(__logf(fmaf(v2.z, sc, 1.f)));
    b.w = f2bu(__logf(fmaf(v2.w, sc, 1.f)));
    *(ushort4*)(xrow + (lane + 128) * 4) = b;
    b.x = f2bu(__logf(fmaf(v3.x, sc, 1.f)));   // lanes >=58: v3=0 -> writes 0 (K pad)
    b.y = f2bu(__logf(fmaf(v3.y, sc, 1.f)));
    b.z = f2bu(__logf(fmaf(v3.z, sc, 1.f)));
    b.w = f2bu(__logf(fmaf(v3.w, sc, 1.f)));
    *(ushort4*)(xrow + (lane + 192) * 4) = b;
  }
}

// ------- parallel 2-level exclusive scan of deg -> row_start, cursor -------
// scan1: per-block (256 elems) sums; also emits dinv
__global__ __launch_bounds__(256) void scan1_k(const int* __restrict__ deg, int n,
                                               int* __restrict__ bsum,
                                               float* __restrict__ dinv) {
  int i = blockIdx.x * 256 + threadIdx.x;
  int v = (i < n) ? deg[i] : 0;
  if (i < n) dinv[i] = rsqrtf((float)v + 1.0f);
  __shared__ int sh[256];
  sh[threadIdx.x] = v;
  __syncthreads();
  for (int off = 128; off > 0; off >>= 1) {
    if (threadIdx.x < off) sh[threadIdx.x] += sh[threadIdx.x + off];
    __syncthreads();
  }
  if (threadIdx.x == 0) bsum[blockIdx.x] = sh[0];
}

// scan23: each block redundantly scans bsum (nb<=256) for its offset, then
// local exclusive scan of its 256 deg entries -> row_start, cursor.
__global__ __launch_bounds__(256) void scan23_k(const int* __restrict__ deg, int n, int E,
                                                const int* __restrict__ bsum, int nb,
                                                int* __restrict__ row_start,
                                                int* __restrict__ cursor) {
  int t = threadIdx.x;
  __shared__ int sb[256];
  __shared__ int boff_s;
  int bv = (t < nb) ? bsum[t] : 0;
  sb[t] = bv;
  __syncthreads();
  for (int off = 1; off < 256; off <<= 1) {  // inclusive scan of block sums
    int u = 0;
    if (t >= off) u = sb[t - off];
    __syncthreads();
    sb[t] += u;
    __syncthreads();
  }
  if (t == (int)blockIdx.x) boff_s = sb[t] - bv;  // exclusive offset for this block
  __syncthreads();
  int boff = boff_s;

  int i = blockIdx.x * 256 + t;
  int v = (i < n) ? deg[i] : 0;
  __shared__ int sh[256];
  sh[t] = v;
  __syncthreads();
  for (int off = 1; off < 256; off <<= 1) {
    int u = 0;
    if (t >= off) u = sh[t - off];
    __syncthreads();
    sh[t] += u;
    __syncthreads();
  }
  if (i < n) {
    int rs = boff + sh[t] - v;  // exclusive
    row_start[i] = rs;
    cursor[i] = rs;
    if (i == n - 1) row_start[n] = E;
  }
}

// ------- GCN aggregation: wave per dst node, half-wave edge pairing ---------
// Edge records ew[j] = {src, weight} sequential 8B; ONE random gather per edge.
__global__ __launch_bounds__(256) void agg_k(const unsigned short* __restrict__ hg,
                                             const float* __restrict__ dinv,
                                             const int* __restrict__ row_start,
                                             const int2* __restrict__ ew,
                                             unsigned short* __restrict__ hout,
                                             float* __restrict__ psum,
                                             float* __restrict__ psum2, int n) {
  const int tid = threadIdx.x, lane = tid & 63, wid = tid >> 6;
  const int half = lane >> 5;          // 0: even edges, 1: odd edges
  const int fl = (lane & 31) * 8;      // first of this lane's 8 features
  int gwave = blockIdx.x * 4 + wid;
  int nw = gridDim.x * 4;
  float bs0 = 0.f, bs1 = 0.f, bs2 = 0.f, bs3 = 0.f;
  float bq0 = 0.f, bq1 = 0.f, bq2 = 0.f, bq3 = 0.f;
  for (int i = gwave; i < n; i += nw) {
    float di = dinv[i];
    float acc[8], f[8];
    {
      uint4 v = *(const uint4*)(hg + (size_t)i * 256 + fl);
      float w0 = half ? 0.f : di * di;
      unpack8(v, f);
#pragma unroll
      for (int q = 0; q < 8; ++q) acc[q] = w0 * f[q];
    }
    int e0 = row_start[i], e1 = row_start[i + 1];
    int j = e0;
    for (; j + 4 <= e1; j += 4) {  // 4 edges per iter: 2 gathers in flight
      int2 eA = ew[j + half];
      int2 eB = ew[j + 2 + half];
      float wA = __int_as_float(eA.y);
      float wB = __int_as_float(eB.y);
      uint4 vA = *(const uint4*)(hg + (size_t)eA.x * 256 + fl);
      uint4 vB = *(const uint4*)(hg + (size_t)eB.x * 256 + fl);
      float fa[8], fb[8];
      unpack8(vA, fa);
      unpack8(vB, fb);
#pragma unroll
      for (int q = 0; q < 8; ++q) acc[q] = fmaf(wA, fa[q], acc[q]);
#pragma unroll
      for (int q = 0; q < 8; ++q) acc[q] = fmaf(wB, fb[q], acc[q]);
    }
    if (j + 2 <= e1) {  // one remaining pair
      int2 eA = ew[j + half];
      float wA = __int_as_float(eA.y);
      uint4 vA = *(const uint4*)(hg + (size_t)eA.x * 256 + fl);
      unpack8(vA, f);
#pragma unroll
      for (int q = 0; q < 8; ++q) acc[q] = fmaf(wA, f[q], acc[q]);
      j += 2;
    }
    if (j < e1 && !half) {  // odd tail edge: half 0 only
      int2 eA = ew[j];
      float wA = __int_as_float(eA.y);
      uint4 vA = *(const uint4*)(hg + (size_t)eA.x * 256 + fl);
      unpack8(vA, f);
#pragma unroll
      for (int q = 0; q < 8; ++q) acc[q] = fmaf(wA, f[q], acc[q]);
    }
#pragma unroll
    for (int q = 0; q < 8; ++q) acc[q] += __shfl_xor(acc[q], 32, 64);
    float o0 = half ? acc[4] : acc[0];
    float o1 = half ? acc[5] : acc[1];
    float o2 = half ? acc[6] : acc[2];
    float o3 = half ? acc[7] : acc[3];
    ushort4 ob;
    ob.x = f2bu(o0); ob.y = f2bu(o1); ob.z = f2bu(o2); ob.w = f2bu(o3);
    *(ushort4*)(hout + (size_t)i * 256 + fl + half * 4) = ob;
    bs0 += o0; bq0 = fmaf(o0, o0, bq0);
    bs1 += o1; bq1 = fmaf(o1, o1, bq1);
    bs2 += o2; bq2 = fmaf(o2, o2, bq2);
    bs3 += o3; bq3 = fmaf(o3, o3, bq3);
  }
  __shared__ float ls[2048];  // [0:1024) sums, [1024:2048) sumsq; [wave][256]
  int fbase = fl + half * 4;
  *(float4*)&ls[wid * 256 + fbase] = (float4){bs0, bs1, bs2, bs3};
  *(float4*)&ls[1024 + wid * 256 + fbase] = (float4){bq0, bq1, bq2, bq3};
  __syncthreads();
  float ss = ls[tid] + ls[256 + tid] + ls[512 + tid] + ls[768 + tid];
  float qq = ls[1024 + tid] + ls[1280 + tid] + ls[1536 + tid] + ls[1792 + tid];
  psum[(size_t)blockIdx.x * 256 + tid] = ss;
  psum2[(size_t)blockIdx.x * 256 + tid] = qq;
}

// ---------------- BN finalize: one block per feature -> affine coefs --------
__global__ __launch_bounds__(256) void bnfinal_k(const float* __restrict__ psum,
                                                 const float* __restrict__ psum2,
                                                 int nb, int n,
                                                 const float* __restrict__ gamma,
                                                 const float* __restrict__ beta,
                                                 float* __restrict__ bnA,
                                                 float* __restrict__ bnB) {
  int f = blockIdx.x;  // 0..255
  int t = threadIdx.x;
  float s = 0.f, s2 = 0.f;
  for (int b = t; b < nb; b += 256) {
    s += psum[(size_t)b * 256 + f];
    s2 += psum2[(size_t)b * 256 + f];
  }
  __shared__ float as[256], as2[256];
  as[t] = s; as2[t] = s2;
  __syncthreads();
  for (int off = 128; off > 0; off >>= 1) {
    if (t < off) { as[t] += as[t + off]; as2[t] += as2[t + off]; }
    __syncthreads();
  }
  if (t == 0) {
    float m = as[0] / n;
    float var = as2[0] / n - m * m;
    float a = gamma[f] * rsqrtf(var + 1e-5f);
    bnA[f] = a;
    bnB[f] = beta[f] - m * a;
  }
}

// ---------- MFMA GEMM: BM x 256 tile, BK=64, 8 waves (2 x 4) ----------
// MODE 0: A = Abf bf16 [nrows][K] via global_load_lds; blocks >= mbG run the
//         edge scatter (fused independent work). BM = 64 or 128.
// MODE 2: A = bf16(leaky(bnA*h + bnB)), h bf16 [nrows][256]; requires BM=128.
template <int KSTEPS, int MODE, int BM>
__global__ __launch_bounds__(512) void gemm_kernel(
    const unsigned short* __restrict__ Abf, const unsigned short* __restrict__ Hb,
    const float* __restrict__ bnA, const float* __restrict__ bnB,
    const unsigned short* __restrict__ BT,
    unsigned short* __restrict__ C, int nrows,
    const int* __restrict__ eip, int E, const float* __restrict__ dinvp,
    int* __restrict__ cursorp, int2* __restrict__ ewp, int mbG) {
  if (MODE == 0 && blockIdx.x >= mbG) {  // fused scatter part
    int e = (blockIdx.x - mbG) * 512 + threadIdx.x;
    int stride = (gridDim.x - mbG) * 512;
    for (; e < E; e += stride) {
      int s = eip[e], d = eip[E + e];
      float w = dinvp[s] * dinvp[d];
      int pos = atomicAdd(&cursorp[d], 1);
      ewp[pos] = make_int2(s, __float_as_int(w));
    }
    return;
  }
  constexpr int MREP = BM / 32;  // acc row-frags per wave (2 wave-rows)
  __shared__ __align__(16) unsigned short At[BM * 64];
  __shared__ __align__(16) unsigned short Bt[256 * 64];
  const int tid = threadIdx.x;
  const int lane = tid & 63;
  const int wid = tid >> 6;
  const int wm = wid >> 2, wn = wid & 3;
  const int brow = blockIdx.x * BM;
  constexpr int K = KSTEPS * 64;

  f32x4 acc[MREP][4];
#pragma unroll
  for (int m = 0; m < MREP; ++m)
#pragma unroll
    for (int n = 0; n < 4; ++n) acc[m][n] = (f32x4){0.f, 0.f, 0.f, 0.f};

  const int rloc = tid >> 4;  // 0..31 (MODE 2 staging)
  const int hc = tid & 15;
  int growA[4];
  if constexpr (MODE == 2) {
#pragma unroll
    for (int p = 0; p < 4; ++p) {
      int r = p * 32 + rloc;
      int g = brow + r;
      if (g > nrows - 1) g = nrows - 1;
      growA[p] = g;
    }
  }

  for (int ks = 0; ks < KSTEPS; ++ks) {
    const int k0 = ks * 64;
#pragma unroll
    for (int is = 0; is < 4; ++is) {
      int n0 = is * 64 + wid * 8;
      int nr = n0 + (lane >> 3);
      int csw = (lane & 7) ^ (lane >> 3);
      gload_lds16(BT + (size_t)nr * K + k0 + csw * 8, Bt + n0 * 64);
    }
    if constexpr (MODE == 0) {
#pragma unroll
      for (int is = 0; is < BM / 64; ++is) {
        int r0 = is * 64 + wid * 8;
        int r = r0 + (lane >> 3);
        int g = brow + r;
        if (g > nrows - 1) g = nrows - 1;
        int csw = (lane & 7) ^ (lane >> 3);
        gload_lds16(Abf + (size_t)g * K + k0 + csw * 8, At + r0 * 64);
      }
    } else {
#pragma unroll
      for (int p = 0; p < 4; ++p) {
        int r = p * 32 + rloc;
        int kk = k0 + hc * 4;
        ushort4 v = *(const ushort4*)(Hb + (size_t)growA[p] * 256 + kk);
        float4 a = *(const float4*)(bnA + kk);
        float4 bb = *(const float4*)(bnB + kk);
        float y0 = fmaf(b2f(v.x), a.x, bb.x); y0 = y0 >= 0.f ? y0 : 0.2f * y0;
        float y1 = fmaf(b2f(v.y), a.y, bb.y); y1 = y1 >= 0.f ? y1 : 0.2f * y1;
        float y2 = fmaf(b2f(v.z), a.z, bb.z); y2 = y2 >= 0.f ? y2 : 0.2f * y2;
        float y3 = fmaf(b2f(v.w), a.w, bb.w); y3 = y3 >= 0.f ? y3 : 0.2f * y3;
        ushort4 b;
        b.x = f2bu(y0); b.y = f2bu(y1); b.z = f2bu(y2); b.w = f2bu(y3);
        *(ushort4*)((char*)At + r * 128 + ((hc * 8) ^ ((r & 7) << 4))) = b;
      }
    }
    __syncthreads();
#pragma unroll
    for (int kk2 = 0; kk2 < 2; ++kk2) {
      const int kb = kk2 * 64 + ((lane >> 4) << 4);
      bf16x8 afr[MREP], bfr[4];
#pragma unroll
      for (int m = 0; m < MREP; ++m) {
        int row = wm * (MREP * 16) + m * 16 + (lane & 15);
        afr[m] = *(const bf16x8*)((const char*)At + row * 128 + (kb ^ ((row & 7) << 4)));
      }
#pragma unroll
      for (int n = 0; n < 4; ++n) {
        int col = wn * 64 + n * 16 + (lane & 15);
        bfr[n] = *(const bf16x8*)((const char*)Bt + col * 128 + (kb ^ ((col & 7) << 4)));
      }
#pragma unroll
      for (int m = 0; m < MREP; ++m)
#pragma unroll
        for (int n = 0; n < 4; ++n)
          acc[m][n] = __builtin_amdgcn_mfma_f32_16x16x32_bf16(afr[m], bfr[n], acc[m][n], 0, 0, 0);
    }
    __syncthreads();
  }
  const int cl = lane & 15;
  const int r4 = (lane >> 4) * 4;
#pragma unroll
  for (int m = 0; m < MREP; ++m) {
    int row0 = brow + wm * (MREP * 16) + m * 16 + r4;
#pragma unroll
    for (int n = 0; n < 4; ++n) {
      int col = wn * 64 + n * 16 + cl;
#pragma unroll
      for (int q = 0; q < 4; ++q) {
        int row = row0 + q;
        if (row < nrows) C[(size_t)row * 256 + col] = f2bu(acc[m][n][q]);
      }
    }
  }
}

// ---- head: A = leaky(bn2 on hout bf16) [nrows][256]; B [64][256] -> loc/std
__global__ __launch_bounds__(256) void head_kernel(
    const unsigned short* __restrict__ Hb, const float* __restrict__ bnA,
    const float* __restrict__ bnB, const unsigned short* __restrict__ BT,
    const float* __restrict__ bloc, const float* __restrict__ bstd,
    float* __restrict__ out, int nrows) {
  __shared__ __align__(16) unsigned short At[128 * 64];
  __shared__ __align__(16) unsigned short Bt[64 * 64];
  const int tid = threadIdx.x, lane = tid & 63, wid = tid >> 6;
  const int wm = wid >> 1, wn = wid & 1;
  const int brow = blockIdx.x * 128;

  f32x4 acc[4][2];
#pragma unroll
  for (int m = 0; m < 4; ++m)
#pragma unroll
    for (int n = 0; n < 2; ++n) acc[m][n] = (f32x4){0.f, 0.f, 0.f, 0.f};

  const int hc = tid & 15;
  for (int ks = 0; ks < 4; ++ks) {
    const int k0 = ks * 64;
#pragma unroll
    for (int is = 0; is < 2; ++is) {  // B: 64 rows
      int n0 = is * 32 + wid * 8;
      int nr = n0 + (lane >> 3);
      int csw = (lane & 7) ^ (lane >> 3);
      gload_lds16(BT + (size_t)nr * 256 + k0 + csw * 8, Bt + n0 * 64);
    }
#pragma unroll
    for (int p = 0; p < 8; ++p) {  // A: 128 rows fused BN+leaky from bf16
      int r = p * 16 + (tid >> 4);
      int g = brow + r;
      if (g > nrows - 1) g = nrows - 1;
      int kk = k0 + hc * 4;
      ushort4 v = *(const ushort4*)(Hb + (size_t)g * 256 + kk);
      float4 a = *(const float4*)(bnA + kk);
      float4 bb = *(const float4*)(bnB + kk);
      float y0 = fmaf(b2f(v.x), a.x, bb.x); y0 = y0 >= 0.f ? y0 : 0.2f * y0;
      float y1 = fmaf(b2f(v.y), a.y, bb.y); y1 = y1 >= 0.f ? y1 : 0.2f * y1;
      float y2 = fmaf(b2f(v.z), a.z, bb.z); y2 = y2 >= 0.f ? y2 : 0.2f * y2;
      float y3 = fmaf(b2f(v.w), a.w, bb.w); y3 = y3 >= 0.f ? y3 : 0.2f * y3;
      ushort4 b;
      b.x = f2bu(y0); b.y = f2bu(y1); b.z = f2bu(y2); b.w = f2bu(y3);
      *(ushort4*)((char*)At + r * 128 + ((hc * 8) ^ ((r & 7) << 4))) = b;
    }
    __syncthreads();
#pragma unroll
    for (int kk2 = 0; kk2 < 2; ++kk2) {
      const int kb = kk2 * 64 + ((lane >> 4) << 4);
      bf16x8 afr[4], bfr[2];
#pragma unroll
      for (int m = 0; m < 4; ++m) {
        int row = wm * 64 + m * 16 + (lane & 15);
        afr[m] = *(const bf16x8*)((const char*)At + row * 128 + (kb ^ ((row & 7) << 4)));
      }
#pragma unroll
      for (int n = 0; n < 2; ++n) {
        int col = wn * 32 + n * 16 + (lane & 15);
        bfr[n] = *(const bf16x8*)((const char*)Bt + col * 128 + (kb ^ ((col & 7) << 4)));
      }
#pragma unroll
      for (int m = 0; m < 4; ++m)
#pragma unroll
        for (int n = 0; n < 2; ++n)
          acc[m][n] = __builtin_amdgcn_mfma_f32_16x16x32_bf16(afr[m], bfr[n], acc[m][n], 0, 0, 0);
    }
    __syncthreads();
  }
  const int cl = lane & 15;
  const int r4 = (lane >> 4) * 4;
  const size_t stdoff = (size_t)nrows * 32;
#pragma unroll
  for (int m = 0; m < 4; ++m) {
    int row0 = brow + wm * 64 + m * 16 + r4;
#pragma unroll
    for (int n = 0; n < 2; ++n) {
      int j = wn * 32 + n * 16 + cl;
#pragma unroll
      for (int q = 0; q < 4; ++q) {
        int row = row0 + q;
        if (row < nrows) {
          float v = acc[m][n][q];
          if (j < 32) {
            out[(size_t)row * 32 + j] = v + bloc[j];
          } else {
            float xx = v + bstd[j - 32];
            float sp = xx > 20.f ? xx : log1pf(__expf(xx));
            out[stdoff + (size_t)row * 32 + (j - 32)] = sp + 1e-7f;
          }
        }
      }
    }
  }
}

// ---------------- host launch ----------------
extern "C" void kernel_launch(void* const* d_in, const int* in_sizes, int n_in,
                              void* d_out, int out_size, void* d_ws, size_t ws_size,
                              hipStream_t stream) {
  const float* x = (const float*)d_in[0];
  const float* W1 = (const float*)d_in[1];
  const float* gamma1 = (const float*)d_in[2];
  const float* beta1 = (const float*)d_in[3];
  const float* W2 = (const float*)d_in[4];
  const float* gamma2 = (const float*)d_in[5];
  const float* beta2 = (const float*)d_in[6];
  const float* Wloc = (const float*)d_in[7];
  const float* bloc = (const float*)d_in[8];
  const float* Wstd = (const float*)d_in[9];
  const float* bstd = (const float*)d_in[10];
  const int* ei = (const int*)d_in[11];

  const int N = out_size / 65;     // 50000
  const int E = in_sizes[11] / 2;  // 800000
  const int AGG_B = 2048;          // agg grid blocks (= BN partial count)
  const int SB = (N + 255) / 256;  // scan blocks (196 for N=50000), must be <=256

  char* w = (char*)d_ws;
  size_t off = 0;
  auto alloc = [&](size_t b) -> void* {
    void* p = w + off;
    off = (off + b + 255) & ~(size_t)255;
    return p;
  };

  unsigned short* xb = (unsigned short*)alloc(2 * (size_t)N * 1024);
  unsigned short* W1T = (unsigned short*)alloc(2 * 256 * 1024);
  unsigned short* W2T = (unsigned short*)alloc(2 * 256 * 256);
  unsigned short* WcT = (unsigned short*)alloc(2 * 64 * 256);
  int* deg = (int*)alloc(4 * (size_t)N);
  float* dinv = (float*)alloc(4 * (size_t)N);
  int* row_start = (int*)alloc(4 * ((size_t)N + 1));
  int* cursor = (int*)alloc(4 * (size_t)N);
  int2* ew = (int2*)alloc(8 * (size_t)E);
  int* bsum = (int*)alloc(4 * 256);
  unsigned short* hg = (unsigned short*)alloc(2 * (size_t)N * 256);
  unsigned short* hout = (unsigned short*)alloc(2 * (size_t)N * 256);
  float* psum = (float*)alloc(4 * (size_t)AGG_B * 256);
  float* psum2 = (float*)alloc(4 * (size_t)AGG_B * 256);
  float* bnA1 = (float*)alloc(4 * 256);
  float* bnB1 = (float*)alloc(4 * 256);
  float* bnA2 = (float*)alloc(4 * 256);
  float* bnB2 = (float*)alloc(4 * 256);
  (void)ws_size;

  float* out = (float*)d_out;
  float* out_l = out + (size_t)N * 64;

  const int mb1 = (N + 63) / 64;    // gemm1 BM=64
  const int mb2 = (N + 127) / 128;  // gemm2/head BM=128

  // prep_w (1344 blocks) + zero(deg) (SB blocks)
  prep_zero_k<<<1344 + SB, 256, 0, stream>>>(W1, W2, Wloc, Wstd, W1T, W2T, WcT, deg, N);
  // rowsum (2048 blocks) || deg histogram (512 blocks)
  rowsum_deg_k<<<2048 + 512, 256, 0, stream>>>(x, out_l, xb, N, ei, E, deg, 2048);

  scan1_k<<<SB, 256, 0, stream>>>(deg, N, bsum, dinv);
  scan23_k<<<SB, 256, 0, stream>>>(deg, N, E, bsum, SB, row_start, cursor);

  // layer 1 GEMM BM=64 (mb1 blocks) || edge scatter (512 blocks)
  gemm_kernel<16, 0, 64><<<mb1 + 512, 512, 0, stream>>>(xb, nullptr, nullptr, nullptr, W1T,
                                                        hg, N, ei, E, dinv, cursor, ew, mb1);
  agg_k<<<AGG_B, 256, 0, stream>>>(hg, dinv, row_start, ew, hout, psum, psum2, N);
  bnfinal_k<<<256, 256, 0, stream>>>(psum, psum2, AGG_B, N, gamma1, beta1, bnA1, bnB1);

  // layer 2 (BN1 apply fused into A-staging), BM=128
  gemm_kernel<4, 2, 128><<<mb2, 512, 0, stream>>>(nullptr, hout, bnA1, bnB1, W2T, hg, N,
                                                  nullptr, 0, nullptr, nullptr, nullptr, mb2);
  agg_k<<<AGG_B, 256, 0, stream>>>(hg, dinv, row_start, ew, hout, psum, psum2, N);
  bnfinal_k<<<256, 256, 0, stream>>>(psum, psum2, AGG_B, N, gamma2, beta2, bnA2, bnB2);

  // heads (BN2 apply fused into A-staging)
  head_kernel<<<mb2, 256, 0, stream>>>(hout, bnA2, bnB2, WcT, bloc, bstd, out, N);
}

// Round 14
// 337.075 us; speedup vs baseline: 1.0327x; 1.0327x over previous
//
#include <hip/hip_runtime.h>
#include <hip/hip_bf16.h>

// DataEncoder: normalize(log CPM) -> GCN(BN,LeakyReLU) x2 -> loc/std heads

typedef float f32x4 __attribute__((ext_vector_type(4)));
typedef __bf16 bf16x8 __attribute__((ext_vector_type(8)));

#define AS1 __attribute__((address_space(1)))
#define AS3 __attribute__((address_space(3)))

__device__ __forceinline__ void gload_lds16(const void* g, void* l) {
  __builtin_amdgcn_global_load_lds((AS1 void*)(g), (AS3 void*)(l), 16, 0, 0);
}

__device__ __forceinline__ unsigned short f2bu(float f) {
  return __builtin_bit_cast(unsigned short, __float2bfloat16(f));
}
__device__ __forceinline__ float b2f(unsigned short u) {
  return __uint_as_float(((unsigned)u) << 16);
}

__device__ __forceinline__ void unpack8(uint4 v, float* f) {
  f[0] = __uint_as_float(v.x << 16);
  f[1] = __uint_as_float(v.x & 0xffff0000u);
  f[2] = __uint_as_float(v.y << 16);
  f[3] = __uint_as_float(v.y & 0xffff0000u);
  f[4] = __uint_as_float(v.z << 16);
  f[5] = __uint_as_float(v.z & 0xffff0000u);
  f[6] = __uint_as_float(v.w << 16);
  f[7] = __uint_as_float(v.w & 0xffff0000u);
}

// ---- fused: weight prep (transpose+bf16) + zero(deg) --------------------
__global__ void prep_zero_k(const float* __restrict__ W1, const float* __restrict__ W2,
                            const float* __restrict__ Wloc, const float* __restrict__ Wstd,
                            unsigned short* __restrict__ W1T, unsigned short* __restrict__ W2T,
                            unsigned short* __restrict__ WcT, int* __restrict__ deg, int n) {
  int id = blockIdx.x * 256 + threadIdx.x;
  if (id < 262144) {                       // W1T [256][1024] (K padded 1000->1024)
    int nn = id >> 10, k = id & 1023;
    W1T[nn * 1024 + k] = (k < 1000) ? f2bu(W1[k * 256 + nn]) : (unsigned short)0;
  } else if (id < 262144 + 65536) {        // W2T [256][256]
    int id2 = id - 262144;
    int nn = id2 >> 8, k = id2 & 255;
    W2T[nn * 256 + k] = f2bu(W2[k * 256 + nn]);
  } else if (id < 262144 + 65536 + 16384) {// WcatT [64][256]: cols 0-31 loc, 32-63 std
    int id3 = id - 262144 - 65536;
    int j = id3 >> 8, k = id3 & 255;
    float v = (j < 32) ? Wloc[k * 32 + j] : Wstd[k * 32 + (j - 32)];
    WcT[j * 256 + k] = f2bu(v);
  } else {                                 // zero deg
    int id4 = id - 344064;
    if (id4 < n) deg[id4] = 0;
  }
}

// ---- fused: row sums+normalize (blocks < RB) || deg atomics (blocks >= RB) ----
__global__ __launch_bounds__(256) void rowsum_deg_k(const float* __restrict__ X,
                                                    float* __restrict__ out_l,
                                                    unsigned short* __restrict__ xb, int n,
                                                    const int* __restrict__ ei, int E,
                                                    int* __restrict__ deg, int RB) {
  if (blockIdx.x >= RB) {  // deg histogram part
    int e = (blockIdx.x - RB) * 256 + threadIdx.x;
    int stride = (gridDim.x - RB) * 256;
    for (; e < E; e += stride) atomicAdd(&deg[ei[E + e]], 1);
    return;
  }
  int gtid = blockIdx.x * 256 + threadIdx.x;
  int wave = gtid >> 6, lane = gtid & 63;
  int nw = (RB * 256) >> 6;
  for (int r = wave; r < n; r += nw) {
    const float4* xr = (const float4*)(X + (size_t)r * 1000);
    float4 v0 = xr[lane];
    float4 v1 = xr[lane + 64];
    float4 v2 = xr[lane + 128];
    float4 v3 = (lane < 58) ? xr[lane + 192] : make_float4(0.f, 0.f, 0.f, 0.f);
    float s = ((v0.x + v0.y) + (v0.z + v0.w)) + ((v1.x + v1.y) + (v1.z + v1.w)) +
              ((v2.x + v2.y) + (v2.z + v2.w)) + ((v3.x + v3.y) + (v3.z + v3.w));
#pragma unroll
    for (int o2 = 32; o2 > 0; o2 >>= 1) s += __shfl_xor(s, o2, 64);
    if (lane == 0) out_l[r] = s;
    float sc = 10000.f / s;
    unsigned short* xrow = xb + (size_t)r * 1024;
    ushort4 b;
    b.x = f2bu(__logf(fmaf(v0.x, sc, 1.f)));
    b.y = f2bu(__logf(fmaf(v0.y, sc, 1.f)));
    b.z = f2bu(__logf(fmaf(v0.z, sc, 1.f)));
    b.w = f2bu(__logf(fmaf(v0.w, sc, 1.f)));
    *(ushort4*)(xrow + lane * 4) = b;
    b.x = f2bu(__logf(fmaf(v1.x, sc, 1.f)));
    b.y = f2bu(__logf(fmaf(v1.y, sc, 1.f)));
    b.z = f2bu(__logf(fmaf(v1.z, sc, 1.f)));
    b.w = f2bu(__logf(fmaf(v1.w, sc, 1.f)));
    *(ushort4*)(xrow + (lane + 64) * 4) = b;
    b.x = f2bu(__logf(fmaf(v2.x, sc, 1.f)));
    b.y = f2bu(__logf(fmaf(v2.y, sc, 1.f)));
    b.z = f2bu(__logf(fmaf(v2.z, sc, 1.f)));
    b.w = f2bu(__logf(fmaf(v2.w, sc, 1.f)));
    *(ushort4*)(xrow + (lane + 128) * 4) = b;
    b.x = f2bu(__logf(fmaf(v3.x, sc, 1.f)));   // lanes >=58: v3=0 -> writes 0 (K pad)
    b.y = f2bu(__logf(fmaf(v3.y, sc, 1.f)));
    b.z = f2bu(__logf(fmaf(v3.z, sc, 1.f)));
    b.w = f2bu(__logf(fmaf(v3.w, sc, 1.f)));
    *(ushort4*)(xrow + (lane + 192) * 4) = b;
  }
}

// ------- parallel 2-level exclusive scan of deg -> row_start, cursor -------
// scan1: per-block (256 elems) sums; also emits dinv
__global__ __launch_bounds__(256) void scan1_k(const int* __restrict__ deg, int n,
                                               int* __restrict__ bsum,
                                               float* __restrict__ dinv) {
  int i = blockIdx.x * 256 + threadIdx.x;
  int v = (i < n) ? deg[i] : 0;
  if (i < n) dinv[i] = rsqrtf((float)v + 1.0f);
  __shared__ int sh[256];
  sh[threadIdx.x] = v;
  __syncthreads();
  for (int off = 128; off > 0; off >>= 1) {
    if (threadIdx.x < off) sh[threadIdx.x] += sh[threadIdx.x + off];
    __syncthreads();
  }
  if (threadIdx.x == 0) bsum[blockIdx.x] = sh[0];
}

// scan23: each block redundantly scans bsum (nb<=256) for its offset, then
// local exclusive scan of its 256 deg entries -> row_start, cursor.
__global__ __launch_bounds__(256) void scan23_k(const int* __restrict__ deg, int n, int E,
                                                const int* __restrict__ bsum, int nb,
                                                int* __restrict__ row_start,
                                                int* __restrict__ cursor) {
  int t = threadIdx.x;
  __shared__ int sb[256];
  __shared__ int boff_s;
  int bv = (t < nb) ? bsum[t] : 0;
  sb[t] = bv;
  __syncthreads();
  for (int off = 1; off < 256; off <<= 1) {  // inclusive scan of block sums
    int u = 0;
    if (t >= off) u = sb[t - off];
    __syncthreads();
    sb[t] += u;
    __syncthreads();
  }
  if (t == (int)blockIdx.x) boff_s = sb[t] - bv;  // exclusive offset for this block
  __syncthreads();
  int boff = boff_s;

  int i = blockIdx.x * 256 + t;
  int v = (i < n) ? deg[i] : 0;
  __shared__ int sh[256];
  sh[t] = v;
  __syncthreads();
  for (int off = 1; off < 256; off <<= 1) {
    int u = 0;
    if (t >= off) u = sh[t - off];
    __syncthreads();
    sh[t] += u;
    __syncthreads();
  }
  if (i < n) {
    int rs = boff + sh[t] - v;  // exclusive
    row_start[i] = rs;
    cursor[i] = rs;
    if (i == n - 1) row_start[n] = E;
  }
}

// ------- GCN aggregation: wave per dst node, half-wave edge pairing ---------
// Edge records ew[j] = {src, weight} sequential 8B; ONE random gather per edge.
__global__ __launch_bounds__(256) void agg_k(const unsigned short* __restrict__ hg,
                                             const float* __restrict__ dinv,
                                             const int* __restrict__ row_start,
                                             const int2* __restrict__ ew,
                                             unsigned short* __restrict__ hout,
                                             float* __restrict__ psum,
                                             float* __restrict__ psum2, int n) {
  const int tid = threadIdx.x, lane = tid & 63, wid = tid >> 6;
  const int half = lane >> 5;          // 0: even edges, 1: odd edges
  const int fl = (lane & 31) * 8;      // first of this lane's 8 features
  int gwave = blockIdx.x * 4 + wid;
  int nw = gridDim.x * 4;
  float bs0 = 0.f, bs1 = 0.f, bs2 = 0.f, bs3 = 0.f;
  float bq0 = 0.f, bq1 = 0.f, bq2 = 0.f, bq3 = 0.f;
  for (int i = gwave; i < n; i += nw) {
    float di = dinv[i];
    float acc[8], f[8];
    {
      uint4 v = *(const uint4*)(hg + (size_t)i * 256 + fl);
      float w0 = half ? 0.f : di * di;
      unpack8(v, f);
#pragma unroll
      for (int q = 0; q < 8; ++q) acc[q] = w0 * f[q];
    }
    int e0 = row_start[i], e1 = row_start[i + 1];
    int j = e0;
    for (; j + 4 <= e1; j += 4) {  // 4 edges per iter: 2 gathers in flight
      int2 eA = ew[j + half];
      int2 eB = ew[j + 2 + half];
      float wA = __int_as_float(eA.y);
      float wB = __int_as_float(eB.y);
      uint4 vA = *(const uint4*)(hg + (size_t)eA.x * 256 + fl);
      uint4 vB = *(const uint4*)(hg + (size_t)eB.x * 256 + fl);
      float fa[8], fb[8];
      unpack8(vA, fa);
      unpack8(vB, fb);
#pragma unroll
      for (int q = 0; q < 8; ++q) acc[q] = fmaf(wA, fa[q], acc[q]);
#pragma unroll
      for (int q = 0; q < 8; ++q) acc[q] = fmaf(wB, fb[q], acc[q]);
    }
    if (j + 2 <= e1) {  // one remaining pair
      int2 eA = ew[j + half];
      float wA = __int_as_float(eA.y);
      uint4 vA = *(const uint4*)(hg + (size_t)eA.x * 256 + fl);
      unpack8(vA, f);
#pragma unroll
      for (int q = 0; q < 8; ++q) acc[q] = fmaf(wA, f[q], acc[q]);
      j += 2;
    }
    if (j < e1 && !half) {  // odd tail edge: half 0 only
      int2 eA = ew[j];
      float wA = __int_as_float(eA.y);
      uint4 vA = *(const uint4*)(hg + (size_t)eA.x * 256 + fl);
      unpack8(vA, f);
#pragma unroll
      for (int q = 0; q < 8; ++q) acc[q] = fmaf(wA, f[q], acc[q]);
    }
#pragma unroll
    for (int q = 0; q < 8; ++q) acc[q] += __shfl_xor(acc[q], 32, 64);
    float o0 = half ? acc[4] : acc[0];
    float o1 = half ? acc[5] : acc[1];
    float o2 = half ? acc[6] : acc[2];
    float o3 = half ? acc[7] : acc[3];
    ushort4 ob;
    ob.x = f2bu(o0); ob.y = f2bu(o1); ob.z = f2bu(o2); ob.w = f2bu(o3);
    *(ushort4*)(hout + (size_t)i * 256 + fl + half * 4) = ob;
    bs0 += o0; bq0 = fmaf(o0, o0, bq0);
    bs1 += o1; bq1 = fmaf(o1, o1, bq1);
    bs2 += o2; bq2 = fmaf(o2, o2, bq2);
    bs3 += o3; bq3 = fmaf(o3, o3, bq3);
  }
  __shared__ float ls[2048];  // [0:1024) sums, [1024:2048) sumsq; [wave][256]
  int fbase = fl + half * 4;
  *(float4*)&ls[wid * 256 + fbase] = (float4){bs0, bs1, bs2, bs3};
  *(float4*)&ls[1024 + wid * 256 + fbase] = (float4){bq0, bq1, bq2, bq3};
  __syncthreads();
  float ss = ls[tid] + ls[256 + tid] + ls[512 + tid] + ls[768 + tid];
  float qq = ls[1024 + tid] + ls[1280 + tid] + ls[1536 + tid] + ls[1792 + tid];
  psum[(size_t)blockIdx.x * 256 + tid] = ss;
  psum2[(size_t)blockIdx.x * 256 + tid] = qq;
}

// ---------------- BN finalize: one block per feature -> affine coefs --------
__global__ __launch_bounds__(256) void bnfinal_k(const float* __restrict__ psum,
                                                 const float* __restrict__ psum2,
                                                 int nb, int n,
                                                 const float* __restrict__ gamma,
                                                 const float* __restrict__ beta,
                                                 float* __restrict__ bnA,
                                                 float* __restrict__ bnB) {
  int f = blockIdx.x;  // 0..255
  int t = threadIdx.x;
  float s = 0.f, s2 = 0.f;
  for (int b = t; b < nb; b += 256) {
    s += psum[(size_t)b * 256 + f];
    s2 += psum2[(size_t)b * 256 + f];
  }
  __shared__ float as[256], as2[256];
  as[t] = s; as2[t] = s2;
  __syncthreads();
  for (int off = 128; off > 0; off >>= 1) {
    if (t < off) { as[t] += as[t + off]; as2[t] += as2[t + off]; }
    __syncthreads();
  }
  if (t == 0) {
    float m = as[0] / n;
    float var = as2[0] / n - m * m;
    float a = gamma[f] * rsqrtf(var + 1e-5f);
    bnA[f] = a;
    bnB[f] = beta[f] - m * a;
  }
}

// ---------------- MFMA GEMM: BM=128, BN=256, BK=64, 8 waves ----------------
// MODE 0: A = Abf bf16 [nrows][K] via global_load_lds; blocks >= mbG run the
//         edge scatter (fused independent work).
// MODE 2: A = bf16(leaky(bnA*h + bnB)), h bf16 [nrows][256]
template <int KSTEPS, int MODE>
__global__ __launch_bounds__(512) void gemm_kernel(
    const unsigned short* __restrict__ Abf, const unsigned short* __restrict__ Hb,
    const float* __restrict__ bnA, const float* __restrict__ bnB,
    const unsigned short* __restrict__ BT,
    unsigned short* __restrict__ C, int nrows,
    const int* __restrict__ eip, int E, const float* __restrict__ dinvp,
    int* __restrict__ cursorp, int2* __restrict__ ewp, int mbG) {
  if (MODE == 0 && blockIdx.x >= mbG) {  // fused scatter part
    int e = (blockIdx.x - mbG) * 512 + threadIdx.x;
    int stride = (gridDim.x - mbG) * 512;
    for (; e < E; e += stride) {
      int s = eip[e], d = eip[E + e];
      float w = dinvp[s] * dinvp[d];
      int pos = atomicAdd(&cursorp[d], 1);
      ewp[pos] = make_int2(s, __float_as_int(w));
    }
    return;
  }
  __shared__ __align__(16) unsigned short At[128 * 64];
  __shared__ __align__(16) unsigned short Bt[256 * 64];
  const int tid = threadIdx.x;
  const int lane = tid & 63;
  const int wid = tid >> 6;
  const int wm = wid >> 2, wn = wid & 3;
  const int brow = blockIdx.x * 128;
  constexpr int K = KSTEPS * 64;

  f32x4 acc[4][4];
#pragma unroll
  for (int m = 0; m < 4; ++m)
#pragma unroll
    for (int n = 0; n < 4; ++n) acc[m][n] = (f32x4){0.f, 0.f, 0.f, 0.f};

  const int rloc = tid >> 4;  // 0..31 (MODE 2 staging)
  const int hc = tid & 15;
  int growA[4];
  if constexpr (MODE == 2) {
#pragma unroll
    for (int p = 0; p < 4; ++p) {
      int r = p * 32 + rloc;
      int g = brow + r;
      if (g > nrows - 1) g = nrows - 1;
      growA[p] = g;
    }
  }

  for (int ks = 0; ks < KSTEPS; ++ks) {
    const int k0 = ks * 64;
#pragma unroll
    for (int is = 0; is < 4; ++is) {
      int n0 = is * 64 + wid * 8;
      int nr = n0 + (lane >> 3);
      int csw = (lane & 7) ^ (lane >> 3);
      gload_lds16(BT + (size_t)nr * K + k0 + csw * 8, Bt + n0 * 64);
    }
    if constexpr (MODE == 0) {
#pragma unroll
      for (int is = 0; is < 2; ++is) {
        int r0 = is * 64 + wid * 8;
        int r = r0 + (lane >> 3);
        int g = brow + r;
        if (g > nrows - 1) g = nrows - 1;
        int csw = (lane & 7) ^ (lane >> 3);
        gload_lds16(Abf + (size_t)g * K + k0 + csw * 8, At + r0 * 64);
      }
    } else {
#pragma unroll
      for (int p = 0; p < 4; ++p) {
        int r = p * 32 + rloc;
        int kk = k0 + hc * 4;
        ushort4 v = *(const ushort4*)(Hb + (size_t)growA[p] * 256 + kk);
        float4 a = *(const float4*)(bnA + kk);
        float4 bb = *(const float4*)(bnB + kk);
        float y0 = fmaf(b2f(v.x), a.x, bb.x); y0 = y0 >= 0.f ? y0 : 0.2f * y0;
        float y1 = fmaf(b2f(v.y), a.y, bb.y); y1 = y1 >= 0.f ? y1 : 0.2f * y1;
        float y2 = fmaf(b2f(v.z), a.z, bb.z); y2 = y2 >= 0.f ? y2 : 0.2f * y2;
        float y3 = fmaf(b2f(v.w), a.w, bb.w); y3 = y3 >= 0.f ? y3 : 0.2f * y3;
        ushort4 b;
        b.x = f2bu(y0); b.y = f2bu(y1); b.z = f2bu(y2); b.w = f2bu(y3);
        *(ushort4*)((char*)At + r * 128 + ((hc * 8) ^ ((r & 7) << 4))) = b;
      }
    }
    __syncthreads();
#pragma unroll
    for (int kk2 = 0; kk2 < 2; ++kk2) {
      const int kb = kk2 * 64 + ((lane >> 4) << 4);
      bf16x8 afr[4], bfr[4];
#pragma unroll
      for (int m = 0; m < 4; ++m) {
        int row = wm * 64 + m * 16 + (lane & 15);
        afr[m] = *(const bf16x8*)((const char*)At + row * 128 + (kb ^ ((row & 7) << 4)));
      }
#pragma unroll
      for (int n = 0; n < 4; ++n) {
        int col = wn * 64 + n * 16 + (lane & 15);
        bfr[n] = *(const bf16x8*)((const char*)Bt + col * 128 + (kb ^ ((col & 7) << 4)));
      }
#pragma unroll
      for (int m = 0; m < 4; ++m)
#pragma unroll
        for (int n = 0; n < 4; ++n)
          acc[m][n] = __builtin_amdgcn_mfma_f32_16x16x32_bf16(afr[m], bfr[n], acc[m][n], 0, 0, 0);
    }
    __syncthreads();
  }
  const int cl = lane & 15;
  const int r4 = (lane >> 4) * 4;
#pragma unroll
  for (int m = 0; m < 4; ++m) {
    int row0 = brow + wm * 64 + m * 16 + r4;
#pragma unroll
    for (int n = 0; n < 4; ++n) {
      int col = wn * 64 + n * 16 + cl;
#pragma unroll
      for (int q = 0; q < 4; ++q) {
        int row = row0 + q;
        if (row < nrows) C[(size_t)row * 256 + col] = f2bu(acc[m][n][q]);
      }
    }
  }
}

// ---- head: A = leaky(bn2 on hout bf16) [nrows][256]; B [64][256] -> loc/std
__global__ __launch_bounds__(256) void head_kernel(
    const unsigned short* __restrict__ Hb, const float* __restrict__ bnA,
    const float* __restrict__ bnB, const unsigned short* __restrict__ BT,
    const float* __restrict__ bloc, const float* __restrict__ bstd,
    float* __restrict__ out, int nrows) {
  __shared__ __align__(16) unsigned short At[128 * 64];
  __shared__ __align__(16) unsigned short Bt[64 * 64];
  const int tid = threadIdx.x, lane = tid & 63, wid = tid >> 6;
  const int wm = wid >> 1, wn = wid & 1;
  const int brow = blockIdx.x * 128;

  f32x4 acc[4][2];
#pragma unroll
  for (int m = 0; m < 4; ++m)
#pragma unroll
    for (int n = 0; n < 2; ++n) acc[m][n] = (f32x4){0.f, 0.f, 0.f, 0.f};

  const int hc = tid & 15;
  for (int ks = 0; ks < 4; ++ks) {
    const int k0 = ks * 64;
#pragma unroll
    for (int is = 0; is < 2; ++is) {  // B: 64 rows
      int n0 = is * 32 + wid * 8;
      int nr = n0 + (lane >> 3);
      int csw = (lane & 7) ^ (lane >> 3);
      gload_lds16(BT + (size_t)nr * 256 + k0 + csw * 8, Bt + n0 * 64);
    }
#pragma unroll
    for (int p = 0; p < 8; ++p) {  // A: 128 rows fused BN+leaky from bf16
      int r = p * 16 + (tid >> 4);
      int g = brow + r;
      if (g > nrows - 1) g = nrows - 1;
      int kk = k0 + hc * 4;
      ushort4 v = *(const ushort4*)(Hb + (size_t)g * 256 + kk);
      float4 a = *(const float4*)(bnA + kk);
      float4 bb = *(const float4*)(bnB + kk);
      float y0 = fmaf(b2f(v.x), a.x, bb.x); y0 = y0 >= 0.f ? y0 : 0.2f * y0;
      float y1 = fmaf(b2f(v.y), a.y, bb.y); y1 = y1 >= 0.f ? y1 : 0.2f * y1;
      float y2 = fmaf(b2f(v.z), a.z, bb.z); y2 = y2 >= 0.f ? y2 : 0.2f * y2;
      float y3 = fmaf(b2f(v.w), a.w, bb.w); y3 = y3 >= 0.f ? y3 : 0.2f * y3;
      ushort4 b;
      b.x = f2bu(y0); b.y = f2bu(y1); b.z = f2bu(y2); b.w = f2bu(y3);
      *(ushort4*)((char*)At + r * 128 + ((hc * 8) ^ ((r & 7) << 4))) = b;
    }
    __syncthreads();
#pragma unroll
    for (int kk2 = 0; kk2 < 2; ++kk2) {
      const int kb = kk2 * 64 + ((lane >> 4) << 4);
      bf16x8 afr[4], bfr[2];
#pragma unroll
      for (int m = 0; m < 4; ++m) {
        int row = wm * 64 + m * 16 + (lane & 15);
        afr[m] = *(const bf16x8*)((const char*)At + row * 128 + (kb ^ ((row & 7) << 4)));
      }
#pragma unroll
      for (int n = 0; n < 2; ++n) {
        int col = wn * 32 + n * 16 + (lane & 15);
        bfr[n] = *(const bf16x8*)((const char*)Bt + col * 128 + (kb ^ ((col & 7) << 4)));
      }
#pragma unroll
      for (int m = 0; m < 4; ++m)
#pragma unroll
        for (int n = 0; n < 2; ++n)
          acc[m][n] = __builtin_amdgcn_mfma_f32_16x16x32_bf16(afr[m], bfr[n], acc[m][n], 0, 0, 0);
    }
    __syncthreads();
  }
  const int cl = lane & 15;
  const int r4 = (lane >> 4) * 4;
  const size_t stdoff = (size_t)nrows * 32;
#pragma unroll
  for (int m = 0; m < 4; ++m) {
    int row0 = brow + wm * 64 + m * 16 + r4;
#pragma unroll
    for (int n = 0; n < 2; ++n) {
      int j = wn * 32 + n * 16 + cl;
#pragma unroll
      for (int q = 0; q < 4; ++q) {
        int row = row0 + q;
        if (row < nrows) {
          float v = acc[m][n][q];
          if (j < 32) {
            out[(size_t)row * 32 + j] = v + bloc[j];
          } else {
            float xx = v + bstd[j - 32];
            float sp = xx > 20.f ? xx : log1pf(__expf(xx));
            out[stdoff + (size_t)row * 32 + (j - 32)] = sp + 1e-7f;
          }
        }
      }
    }
  }
}

// ---------------- host launch ----------------
extern "C" void kernel_launch(void* const* d_in, const int* in_sizes, int n_in,
                              void* d_out, int out_size, void* d_ws, size_t ws_size,
                              hipStream_t stream) {
  const float* x = (const float*)d_in[0];
  const float* W1 = (const float*)d_in[1];
  const float* gamma1 = (const float*)d_in[2];
  const float* beta1 = (const float*)d_in[3];
  const float* W2 = (const float*)d_in[4];
  const float* gamma2 = (const float*)d_in[5];
  const float* beta2 = (const float*)d_in[6];
  const float* Wloc = (const float*)d_in[7];
  const float* bloc = (const float*)d_in[8];
  const float* Wstd = (const float*)d_in[9];
  const float* bstd = (const float*)d_in[10];
  const int* ei = (const int*)d_in[11];

  const int N = out_size / 65;     // 50000
  const int E = in_sizes[11] / 2;  // 800000
  const int AGG_B = 2048;          // agg grid blocks (= BN partial count)
  const int SB = (N + 255) / 256;  // scan blocks (196 for N=50000), must be <=256

  char* w = (char*)d_ws;
  size_t off = 0;
  auto alloc = [&](size_t b) -> void* {
    void* p = w + off;
    off = (off + b + 255) & ~(size_t)255;
    return p;
  };

  unsigned short* xb = (unsigned short*)alloc(2 * (size_t)N * 1024);
  unsigned short* W1T = (unsigned short*)alloc(2 * 256 * 1024);
  unsigned short* W2T = (unsigned short*)alloc(2 * 256 * 256);
  unsigned short* WcT = (unsigned short*)alloc(2 * 64 * 256);
  int* deg = (int*)alloc(4 * (size_t)N);
  float* dinv = (float*)alloc(4 * (size_t)N);
  int* row_start = (int*)alloc(4 * ((size_t)N + 1));
  int* cursor = (int*)alloc(4 * (size_t)N);
  int2* ew = (int2*)alloc(8 * (size_t)E);
  int* bsum = (int*)alloc(4 * 256);
  unsigned short* hg = (unsigned short*)alloc(2 * (size_t)N * 256);
  unsigned short* hout = (unsigned short*)alloc(2 * (size_t)N * 256);
  float* psum = (float*)alloc(4 * (size_t)AGG_B * 256);
  float* psum2 = (float*)alloc(4 * (size_t)AGG_B * 256);
  float* bnA1 = (float*)alloc(4 * 256);
  float* bnB1 = (float*)alloc(4 * 256);
  float* bnA2 = (float*)alloc(4 * 256);
  float* bnB2 = (float*)alloc(4 * 256);
  (void)ws_size;

  float* out = (float*)d_out;
  float* out_l = out + (size_t)N * 64;

  const int mb = (N + 127) / 128;

  // prep_w (1344 blocks) + zero(deg) (SB blocks)
  prep_zero_k<<<1344 + SB, 256, 0, stream>>>(W1, W2, Wloc, Wstd, W1T, W2T, WcT, deg, N);
  // rowsum (2048 blocks) || deg histogram (512 blocks)
  rowsum_deg_k<<<2048 + 512, 256, 0, stream>>>(x, out_l, xb, N, ei, E, deg, 2048);

  scan1_k<<<SB, 256, 0, stream>>>(deg, N, bsum, dinv);
  scan23_k<<<SB, 256, 0, stream>>>(deg, N, E, bsum, SB, row_start, cursor);

  // layer 1 GEMM BM=128 (mb blocks) || edge scatter (512 blocks)
  gemm_kernel<16, 0><<<mb + 512, 512, 0, stream>>>(xb, nullptr, nullptr, nullptr, W1T, hg, N,
                                                   ei, E, dinv, cursor, ew, mb);
  agg_k<<<AGG_B, 256, 0, stream>>>(hg, dinv, row_start, ew, hout, psum, psum2, N);
  bnfinal_k<<<256, 256, 0, stream>>>(psum, psum2, AGG_B, N, gamma1, beta1, bnA1, bnB1);

  // layer 2 (BN1 apply fused into A-staging)
  gemm_kernel<4, 2><<<mb, 512, 0, stream>>>(nullptr, hout, bnA1, bnB1, W2T, hg, N,
                                            nullptr, 0, nullptr, nullptr, nullptr, mb);
  agg_k<<<AGG_B, 256, 0, stream>>>(hg, dinv, row_start, ew, hout, psum, psum2, N);
  bnfinal_k<<<256, 256, 0, stream>>>(psum, psum2, AGG_B, N, gamma2, beta2, bnA2, bnB2);

  // heads (BN2 apply fused into A-staging)
  head_kernel<<<mb, 256, 0, stream>>>(hout, bnA2, bnB2, WcT, bloc, bstd, out, N);
}